// Round 1
// baseline (375.521 us; speedup 1.0000x reference)
//
#include <hip/hip_runtime.h>
#include <hip/hip_bf16.h>

// Problem: X = Z * G, G = (I - tril(A_raw,-1))^{-1}  (unit lower-triangular 256x256)
// Z: [131072 x 256] fp32, Out: [131072 x 256] fp32.

typedef __bf16 bf16x8 __attribute__((ext_vector_type(8)));
typedef float f32x4 __attribute__((ext_vector_type(4)));

__device__ __forceinline__ unsigned short f2bf(float f) {
    union { float f; unsigned u; } v; v.f = f;
    unsigned u = v.u;
    u += 0x7FFFu + ((u >> 16) & 1u);   // round-to-nearest-even
    return (unsigned short)(u >> 16);
}

// ---------------------------------------------------------------------------
// Kernel 1: G = (I - A)^{-1}, one wave per column c, forward substitution.
// Lane l owns g[l], g[64+l], g[128+l], g[192+l] in registers.
// Stores G transposed: Gt[c*256 + j] = G[j][c]  (bf16), so the GEMM reads
// B-fragments as contiguous 16B runs (B^T layout).
// ---------------------------------------------------------------------------
__global__ __launch_bounds__(64) void make_G(const float* __restrict__ A,
                                             unsigned short* __restrict__ Gt) {
    const int c = blockIdx.x;
    const int l = threadIdx.x;
    float g0 = (l == c)       ? 1.f : 0.f;
    float g1 = (64 + l == c)  ? 1.f : 0.f;
    float g2 = (128 + l == c) ? 1.f : 0.f;
    float g3 = (192 + l == c) ? 1.f : 0.f;
#pragma unroll
    for (int blk = 0; blk < 4; ++blk) {
        for (int ii = 0; ii < 64; ++ii) {
            const int i = blk * 64 + ii;
            if (i <= c) continue;                 // uniform branch (c is block-uniform)
            const float* Ai = A + i * 256;
            float p = 0.f;
            if (l < i)       p += Ai[l]       * g0;   // strictly-lower mask j < i
            if (64 + l < i)  p += Ai[64 + l]  * g1;
            if (128 + l < i) p += Ai[128 + l] * g2;
            if (192 + l < i) p += Ai[192 + l] * g3;
            p += __shfl_xor(p, 32);
            p += __shfl_xor(p, 16);
            p += __shfl_xor(p, 8);
            p += __shfl_xor(p, 4);
            p += __shfl_xor(p, 2);
            p += __shfl_xor(p, 1);
            if (ii == l) {
                if (blk == 0)      g0 = p;
                else if (blk == 1) g1 = p;
                else if (blk == 2) g2 = p;
                else               g3 = p;
            }
        }
    }
    unsigned short* row = Gt + c * 256;
    row[l]        = f2bf(g0);
    row[64 + l]   = f2bf(g1);
    row[128 + l]  = f2bf(g2);
    row[192 + l]  = f2bf(g3);
}

// ---------------------------------------------------------------------------
// Kernel 2: Out = Z @ G, via Out[b,i] = sum_j Z[b,j] * Gt[i][j].
// BM=128, BN=128, BK=32; 256 threads = 4 waves; wave -> 64x64 via 4x4 MFMA
// 16x16x32 bf16. LDS tiles are [row][K] bf16 so both fragment loads are
// contiguous ds_read_b128: frag[m=lane&15][k=(lane>>4)*8 + j].
// ---------------------------------------------------------------------------
__global__ __launch_bounds__(256) void scm_gemm(const float* __restrict__ Z,
                                                const unsigned short* __restrict__ Gt,
                                                float* __restrict__ Out) {
    __shared__ __align__(16) unsigned short As[128 * 32];
    __shared__ __align__(16) unsigned short Bs[128 * 32];

    const int tid  = threadIdx.x;
    const int lane = tid & 63;
    const int wave = tid >> 6;
    const int bm = blockIdx.y * 128;     // batch tile
    const int bn = blockIdx.x * 128;     // output-var tile (x fastest -> Z reuse in L2)
    const int wm = (wave & 1) * 64;
    const int wn = (wave >> 1) * 64;
    const int l15  = lane & 15;
    const int quad = lane >> 4;

    f32x4 acc[4][4];
#pragma unroll
    for (int a = 0; a < 4; ++a)
#pragma unroll
        for (int b = 0; b < 4; ++b) {
            f32x4 zero = {0.f, 0.f, 0.f, 0.f};
            acc[a][b] = zero;
        }

    for (int kt = 0; kt < 8; ++kt) {
        const int k0 = kt * 32;
        // ---- stage Z tile (fp32 -> bf16), 1024 float4 loads across 256 thr ----
#pragma unroll
        for (int it = 0; it < 4; ++it) {
            int f   = tid + it * 256;          // 0..1023
            int row = f >> 3;                  // 8 float4 per row
            int c4  = (f & 7) * 4;
            float4 v = *(const float4*)(Z + (size_t)(bm + row) * 256 + k0 + c4);
            unsigned a01 = (unsigned)f2bf(v.x) | ((unsigned)f2bf(v.y) << 16);
            unsigned a23 = (unsigned)f2bf(v.z) | ((unsigned)f2bf(v.w) << 16);
            uint2 packed = make_uint2(a01, a23);
            *(uint2*)(&As[row * 32 + c4]) = packed;
        }
        // ---- stage Gt tile (bf16), 512 x 16B loads ----
#pragma unroll
        for (int it = 0; it < 2; ++it) {
            int f   = tid + it * 256;          // 0..511
            int row = f >> 2;                  // 4 x 16B per row
            int c8  = (f & 3) * 8;
            uint4 v = *(const uint4*)(Gt + (size_t)(bn + row) * 256 + k0 + c8);
            *(uint4*)(&Bs[row * 32 + c8]) = v;
        }
        __syncthreads();

        bf16x8 af[4], bf[4];
#pragma unroll
        for (int t = 0; t < 4; ++t) {
            af[t] = *(const bf16x8*)(&As[(wm + t * 16 + l15) * 32 + quad * 8]);
            bf[t] = *(const bf16x8*)(&Bs[(wn + t * 16 + l15) * 32 + quad * 8]);
        }
#pragma unroll
        for (int tm = 0; tm < 4; ++tm)
#pragma unroll
            for (int tn = 0; tn < 4; ++tn)
                acc[tm][tn] = __builtin_amdgcn_mfma_f32_16x16x32_bf16(
                    af[tm], bf[tn], acc[tm][tn], 0, 0, 0);
        __syncthreads();
    }

    // ---- epilogue: C/D layout col = lane&15, row = quad*4 + r ----
#pragma unroll
    for (int tm = 0; tm < 4; ++tm)
#pragma unroll
        for (int tn = 0; tn < 4; ++tn)
#pragma unroll
            for (int r = 0; r < 4; ++r) {
                int row = bm + wm + tm * 16 + quad * 4 + r;
                int col = bn + wn + tn * 16 + l15;
                Out[(size_t)row * 256 + col] = acc[tm][tn][r];
            }
}

extern "C" void kernel_launch(void* const* d_in, const int* in_sizes, int n_in,
                              void* d_out, int out_size, void* d_ws, size_t ws_size,
                              hipStream_t stream) {
    const float* Z = (const float*)d_in[0];       // [131072 x 256]
    const float* A = (const float*)d_in[1];       // [256 x 256]
    float* Out = (float*)d_out;                   // [131072 x 256]
    unsigned short* Gt = (unsigned short*)d_ws;   // 256*256 bf16 = 128 KB

    hipLaunchKernelGGL(make_G, dim3(256), dim3(64), 0, stream, A, Gt);
    hipLaunchKernelGGL(scm_gemm, dim3(2, 1024), dim3(256), 0, stream, Z, Gt, Out);
}

// Round 2
// 272.448 us; speedup vs baseline: 1.3783x; 1.3783x over previous
//
#include <hip/hip_runtime.h>
#include <hip/hip_bf16.h>

// X = Z * G, G = (I - tril(A_raw,-1))^{-1} (unit lower-triangular 256x256)
// Z: [131072 x 256] fp32, Out: [131072 x 256] fp32.
//
// Kernel 1 (make_G2): right-looking column solve, ONE shuffle per step
//   (vs 6-deep reduce tree), A staged in LDS. 64 blocks x 4 waves = 256 cols.
// Kernel 2 (scm_gemm2): G fully resident in LDS (132 KB padded); Z goes
//   global->register directly (read exactly once); K=256 in one shot;
//   no __syncthreads in the hot loop.

typedef __bf16 bf16x8 __attribute__((ext_vector_type(8)));
typedef float f32x4 __attribute__((ext_vector_type(4)));

__device__ __forceinline__ unsigned short f2bf(float f) {
    union { float f; unsigned u; } v; v.f = f;
    unsigned u = v.u;
    u += 0x7FFFu + ((u >> 16) & 1u);   // RNE
    return (unsigned short)(u >> 16);
}
__device__ __forceinline__ float bf2f(unsigned short u) {
    union { unsigned u; float f; } v; v.u = ((unsigned)u) << 16;
    return v.f;
}
__device__ __forceinline__ bf16x8 pack8(float4 a, float4 b) {
    union { bf16x8 v; __hip_bfloat162 h[4]; } u;
    u.h[0] = __float22bfloat162_rn(make_float2(a.x, a.y));
    u.h[1] = __float22bfloat162_rn(make_float2(a.z, a.w));
    u.h[2] = __float22bfloat162_rn(make_float2(b.x, b.y));
    u.h[3] = __float22bfloat162_rn(make_float2(b.z, b.w));
    return u.v;
}

// ---------------------------------------------------------------------------
// Kernel 1: right-looking forward substitution. Block = 256 thr = 4 waves,
// wave solves column c = blockIdx*4 + wave. A in LDS bf16, row stride 258
// (column reads As[64k+l][i] -> bank l%32, 2-way = free).
// Lane l holds p[k] = running value of G[64k+l][c].
// Step i: g_i finalized in lane (i&63) of bank (i>>6); broadcast; update
// pending rows j>i with A[j][i]*g_i (strictly-lower mask == tril(-1)).
// ---------------------------------------------------------------------------
#define AST 258
__global__ __launch_bounds__(256) void make_G2(const float* __restrict__ A,
                                               unsigned short* __restrict__ Gt) {
    __shared__ unsigned short As[256 * AST];   // 129 KB
    const int tid = threadIdx.x;
    const int l = tid & 63;
    const int wv = tid >> 6;

    // stage A (fp32 -> bf16): wave reads full rows (coalesced float4),
    // writes 2x ushort2 (banks (r+2l)%32 spread, 2-way = free).
    for (int it = 0; it < 64; ++it) {
        const int r = it * 4 + wv;
        const int c0 = l * 4;
        float4 v = *(const float4*)(A + r * 256 + c0);
        ushort2 w01 = make_ushort2(f2bf(v.x), f2bf(v.y));
        ushort2 w23 = make_ushort2(f2bf(v.z), f2bf(v.w));
        *(ushort2*)(&As[r * AST + c0])     = w01;
        *(ushort2*)(&As[r * AST + c0 + 2]) = w23;
    }
    __syncthreads();

    const int c = blockIdx.x * 4 + wv;
    float p[4];
#pragma unroll
    for (int k = 0; k < 4; ++k) p[k] = (64 * k + l == c) ? 1.f : 0.f;

#pragma unroll
    for (int kb = 0; kb < 4; ++kb) {
        const int i0 = (c > 64 * kb) ? c : 64 * kb;
        for (int i = i0; i < 64 * kb + 64; ++i) {
            const int t = i - 64 * kb;
            const float v = __shfl(p[kb], t);   // g_i broadcast — the only shuffle
            // bank kb: mask l > t (strictly below the pivot)
            {
                float a = bf2f(As[(64 * kb + l) * AST + i]);
                p[kb] += (l > t ? a : 0.f) * v;
            }
#pragma unroll
            for (int k = kb + 1; k < 4; ++k) {  // banks fully below: no mask
                float a = bf2f(As[(64 * k + l) * AST + i]);
                p[k] += a * v;
            }
        }
    }
    // Gt[c][j] = G[j][c]
#pragma unroll
    for (int k = 0; k < 4; ++k)
        Gt[c * 256 + 64 * k + l] = f2bf(p[k]);
}

// ---------------------------------------------------------------------------
// Kernel 2: Out = Z @ G with G^T resident in LDS. Block = 1024 thr = 16
// waves, 1 block/CU (LDS 132 KB). Wave tile = 16 rows x 256 cols, K=256 in
// one shot: 16 dwordx4 Z loads -> pack bf16 -> 128 MFMAs. Zero barriers in
// the hot loop. Gs row stride 264 (528 B): b128 B-frag reads cover all 32
// banks uniformly (conflict-neutral), 16B-aligned.
// ---------------------------------------------------------------------------
#define GST 264
__global__ __launch_bounds__(1024) void scm_gemm2(const float* __restrict__ Z,
                                                  const unsigned short* __restrict__ Gt,
                                                  float* __restrict__ Out) {
    __shared__ __align__(16) unsigned short Gs[256 * GST];   // 132 KB
    const int tid = threadIdx.x;

    // stage Gt (dense 128 KB) -> padded LDS: 8192 x 16B chunks / 1024 thr
#pragma unroll
    for (int it = 0; it < 8; ++it) {
        const int chunk = it * 1024 + tid;
        const int row = chunk >> 5;            // 32 chunks per 256-elem row
        const int c8 = (chunk & 31) * 8;
        uint4 v = *(const uint4*)(Gt + row * 256 + c8);
        *(uint4*)(&Gs[row * GST + c8]) = v;    // (row*264+c8)*2: 16B-aligned
    }
    __syncthreads();

    const int lane = tid & 63;
    const int wave = tid >> 6;
    const int n = lane & 15;
    const int quad = lane >> 4;

    int gw = blockIdx.x * 16 + wave;           // 0..4095, then +4096
#pragma unroll
    for (int rep = 0; rep < 2; ++rep, gw += 4096) {
        const int m0 = gw * 16;
        const float* zrow = Z + (size_t)(m0 + n) * 256 + quad * 8;

        f32x4 acc[16];
#pragma unroll
        for (int nt = 0; nt < 16; ++nt) {
            f32x4 zero = {0.f, 0.f, 0.f, 0.f};
            acc[nt] = zero;
        }

#pragma unroll
        for (int half = 0; half < 2; ++half) {
            bf16x8 af[4];
#pragma unroll
            for (int kk = 0; kk < 4; ++kk) {
                const int k0 = half * 128 + kk * 32;
                float4 a = *(const float4*)(zrow + k0);
                float4 b = *(const float4*)(zrow + k0 + 4);
                af[kk] = pack8(a, b);
            }
#pragma unroll
            for (int nt = 0; nt < 16; ++nt) {
                const unsigned short* bp =
                    &Gs[(nt * 16 + n) * GST + half * 128 + quad * 8];
#pragma unroll
                for (int kk = 0; kk < 4; ++kk) {
                    bf16x8 bfrag = *(const bf16x8*)(bp + kk * 32);
                    acc[nt] = __builtin_amdgcn_mfma_f32_16x16x32_bf16(
                        af[kk], bfrag, acc[nt], 0, 0, 0);
                }
            }
        }

        // C/D layout: col = lane&15, row = quad*4 + r
#pragma unroll
        for (int nt = 0; nt < 16; ++nt)
#pragma unroll
            for (int r = 0; r < 4; ++r)
                Out[(size_t)(m0 + quad * 4 + r) * 256 + nt * 16 + n] = acc[nt][r];
    }
}

extern "C" void kernel_launch(void* const* d_in, const int* in_sizes, int n_in,
                              void* d_out, int out_size, void* d_ws, size_t ws_size,
                              hipStream_t stream) {
    const float* Z = (const float*)d_in[0];       // [131072 x 256]
    const float* A = (const float*)d_in[1];       // [256 x 256]
    float* Out = (float*)d_out;                   // [131072 x 256]
    unsigned short* Gt = (unsigned short*)d_ws;   // 256*256 bf16 = 128 KB

    hipLaunchKernelGGL(make_G2, dim3(64), dim3(256), 0, stream, A, Gt);
    hipLaunchKernelGGL(scm_gemm2, dim3(256), dim3(1024), 0, stream, Z, Gt, Out);
}

// Round 3
// 267.590 us; speedup vs baseline: 1.4033x; 1.0182x over previous
//
#include <hip/hip_runtime.h>
#include <hip/hip_bf16.h>

// X = Z * G, G = (I - tril(A_raw,-1))^{-1} (unit lower-triangular 256x256)
// Z: [131072 x 256] fp32, Out: [131072 x 256] fp32.
//
// make_G3: 256 blocks (1 col each). 4-wave A staging into LDS (bf16), wave-0
//   right-looking solve with readlane broadcast (SGPR pivot, ~12cy/step chain),
//   fixed trip counts (pivots < c are zero -> predication-free correctness).
// scm_gemm3: 512 blocks x 8 waves. G resident in LDS (132 KB, XOR-swizzled).
//   Wave = 32 rows x 256 cols. Z loads issued FIRST (before staging) so the
//   HBM stream starts at t=0; B-frag shared across both 16-row halves
//   (2 MFMAs per ds_read_b128); K=256 in one shot; no barriers after staging.

typedef __bf16 bf16x8 __attribute__((ext_vector_type(8)));
typedef float f32x4 __attribute__((ext_vector_type(4)));

__device__ __forceinline__ unsigned short f2bf(float f) {
    union { float f; unsigned u; } v; v.f = f;
    unsigned u = v.u;
    u += 0x7FFFu + ((u >> 16) & 1u);   // RNE
    return (unsigned short)(u >> 16);
}
__device__ __forceinline__ bf16x8 pack8(float4 a, float4 b) {
    union { bf16x8 v; __hip_bfloat162 h[4]; } u;
    u.h[0] = __float22bfloat162_rn(make_float2(a.x, a.y));
    u.h[1] = __float22bfloat162_rn(make_float2(a.z, a.w));
    u.h[2] = __float22bfloat162_rn(make_float2(b.x, b.y));
    u.h[3] = __float22bfloat162_rn(make_float2(b.z, b.w));
    return u.v;
}

// ---------------------------------------------------------------------------
// Kernel 1: G columns, one block per column.
// ---------------------------------------------------------------------------
#define AST 258
__global__ __launch_bounds__(256) void make_G3(const float* __restrict__ A,
                                               unsigned short* __restrict__ Gt) {
    __shared__ unsigned short As[256 * AST];   // 129 KB
    const int tid = threadIdx.x;
    const int l = tid & 63;
    const int wv = tid >> 6;

    // stage A (fp32 -> bf16), coalesced row reads
    for (int it = 0; it < 64; ++it) {
        const int r = it * 4 + wv;
        const int c0 = l * 4;
        float4 v = *(const float4*)(A + r * 256 + c0);
        *(ushort2*)(&As[r * AST + c0])     = make_ushort2(f2bf(v.x), f2bf(v.y));
        *(ushort2*)(&As[r * AST + c0 + 2]) = make_ushort2(f2bf(v.z), f2bf(v.w));
    }
    __syncthreads();
    if (wv != 0) return;                       // staging waves done

    const int c = blockIdx.x;
    float p[4];
#pragma unroll
    for (int k = 0; k < 4; ++k) p[k] = (64 * k + l == c) ? 1.f : 0.f;

    // Right-looking substitution over ALL 256 pivots. Pivots < c have value 0
    // (p untouched there), so their updates are no-ops — no dynamic bounds.
    // Chain per pivot: readlane (uniform SGPR) -> fma. LDS reads off-chain,
    // paired (2 bf16 per ds_read_b32).
#pragma unroll
    for (int kb = 0; kb < 4; ++kb) {
#pragma unroll 8
        for (int i2 = 0; i2 < 32; ++i2) {
            unsigned u[4];
#pragma unroll
            for (int k = 0; k < 4; ++k)
                if (k >= kb)
                    u[k] = *(const unsigned*)(&As[(64 * k + l) * AST + kb * 64 + 2 * i2]);
            const int t0 = 2 * i2, t1 = t0 + 1;
            // pivot t0 (even): value = low bf16
            float s0 = __int_as_float(__builtin_amdgcn_readlane(__float_as_int(p[kb]), t0));
            p[kb] += (l > t0 ? __int_as_float(u[kb] << 16) : 0.f) * s0;
#pragma unroll
            for (int k = 0; k < 4; ++k)
                if (k > kb) p[k] += __int_as_float(u[k] << 16) * s0;
            // pivot t1 (odd): value = high bf16
            float s1 = __int_as_float(__builtin_amdgcn_readlane(__float_as_int(p[kb]), t1));
            p[kb] += (l > t1 ? __int_as_float(u[kb] & 0xffff0000u) : 0.f) * s1;
#pragma unroll
            for (int k = 0; k < 4; ++k)
                if (k > kb) p[k] += __int_as_float(u[k] & 0xffff0000u) * s1;
        }
    }
    // Gt[c][j] = G[j][c]
#pragma unroll
    for (int k = 0; k < 4; ++k)
        Gt[c * 256 + 64 * k + l] = f2bf(p[k]);
}

// ---------------------------------------------------------------------------
// Kernel 2: Out = Z @ G. 512 blocks x 512 thr (8 waves), wave = 32 rows.
// Gs layout: 16B granules, row stride 33 granules (264 el), granule index
// XOR-swizzled with (row&3)<<2 -> B-frag reads conflict-free (2-way max).
// ---------------------------------------------------------------------------
__global__ __launch_bounds__(512, 2) void scm_gemm3(const float* __restrict__ Z,
                                                    const unsigned short* __restrict__ Gt,
                                                    float* __restrict__ Out) {
    __shared__ __align__(16) unsigned short Gs[256 * 264];   // 132 KB
    const int tid = threadIdx.x;
    const int lane = tid & 63;
    const int wave = tid >> 6;
    const int n = lane & 15;
    const int quad = lane >> 4;
    const size_t m0 = (size_t)blockIdx.x * 256 + wave * 32;

    // ---- 1. issue ALL Z loads first: HBM stream starts immediately ----
    float4 zf[2][16];
    const float* zb0 = Z + (m0 + n) * 256 + quad * 8;
    const float* zb1 = zb0 + 16 * 256;
#pragma unroll
    for (int kk = 0; kk < 8; ++kk) {
        zf[0][2 * kk]     = *(const float4*)(zb0 + kk * 32);
        zf[0][2 * kk + 1] = *(const float4*)(zb0 + kk * 32 + 4);
    }
#pragma unroll
    for (int kk = 0; kk < 8; ++kk) {
        zf[1][2 * kk]     = *(const float4*)(zb1 + kk * 32);
        zf[1][2 * kk + 1] = *(const float4*)(zb1 + kk * 32 + 4);
    }

    // ---- 2. stage G (dense 128 KB) with XOR swizzle ----
#pragma unroll
    for (int it = 0; it < 16; ++it) {
        const int chunk = it * 512 + tid;      // 0..8191 16B granules
        const int row = chunk >> 5;
        const int g = chunk & 31;
        const int gs = g ^ ((row & 3) << 2);
        uint4 v = *(const uint4*)(Gt + row * 256 + g * 8);
        *(uint4*)(&Gs[(row * 33 + gs) * 8]) = v;
    }
    __syncthreads();

    // ---- 3. pack Z -> bf16 A-frags (data has arrived: barrier drained vmem) ----
    bf16x8 af[2][8];
#pragma unroll
    for (int h = 0; h < 2; ++h)
#pragma unroll
        for (int kk = 0; kk < 8; ++kk)
            af[h][kk] = pack8(zf[h][2 * kk], zf[h][2 * kk + 1]);

    // ---- 4. MFMA: B-frag read once, used by both 16-row halves ----
    f32x4 acc[2][16];
#pragma unroll
    for (int h = 0; h < 2; ++h)
#pragma unroll
        for (int nt = 0; nt < 16; ++nt) {
            f32x4 zero = {0.f, 0.f, 0.f, 0.f};
            acc[h][nt] = zero;
        }
    const int swz = (n & 3) << 2;
#pragma unroll
    for (int kk = 0; kk < 8; ++kk) {
#pragma unroll
        for (int nt = 0; nt < 16; ++nt) {
            const bf16x8 bfr = *(const bf16x8*)(
                &Gs[((nt * 16 + n) * 33 + ((kk * 4 + quad) ^ swz)) * 8]);
            acc[0][nt] = __builtin_amdgcn_mfma_f32_16x16x32_bf16(
                af[0][kk], bfr, acc[0][nt], 0, 0, 0);
            acc[1][nt] = __builtin_amdgcn_mfma_f32_16x16x32_bf16(
                af[1][kk], bfr, acc[1][nt], 0, 0, 0);
        }
    }

    // ---- 5. epilogue: C/D layout col = lane&15, row = quad*4 + r ----
#pragma unroll
    for (int h = 0; h < 2; ++h)
#pragma unroll
        for (int nt = 0; nt < 16; ++nt)
#pragma unroll
            for (int r = 0; r < 4; ++r)
                Out[(m0 + h * 16 + quad * 4 + r) * 256 + nt * 16 + n] = acc[h][nt][r];
}

extern "C" void kernel_launch(void* const* d_in, const int* in_sizes, int n_in,
                              void* d_out, int out_size, void* d_ws, size_t ws_size,
                              hipStream_t stream) {
    const float* Z = (const float*)d_in[0];       // [131072 x 256]
    const float* A = (const float*)d_in[1];       // [256 x 256]
    float* Out = (float*)d_out;                   // [131072 x 256]
    unsigned short* Gt = (unsigned short*)d_ws;   // 256*256 bf16 = 128 KB

    hipLaunchKernelGGL(make_G3, dim3(256), dim3(256), 0, stream, A, Gt);
    hipLaunchKernelGGL(scm_gemm3, dim3(512), dim3(512), 0, stream, Z, Gt, Out);
}

// Round 4
// 266.950 us; speedup vs baseline: 1.4067x; 1.0024x over previous
//
#include <hip/hip_runtime.h>
#include <hip/hip_bf16.h>

// X = Z * G, G = (I - tril(A_raw,-1))^{-1} (unit lower-triangular 256x256)
// Z: [131072 x 256] fp32, Out: [131072 x 256] fp32.
//
// make_G3 (unchanged): 256 blocks, right-looking solve, readlane broadcast.
// scm_gemm4: N split in 2 -> Gs = 64 KB -> 2 blocks/CU co-resident (the
//   inter-block overlap gemm2/3 lacked). 512 blocks x 512 thr, persistent
//   4-iter M-loop per block, no barriers in the loop, half-K software
//   pipeline (pack K-lo / issue K-hi loads / MFMA / pack K-hi / issue next
//   K-lo / MFMA / store). Registers budgeted for 4 waves/SIMD.

typedef __bf16 bf16x8 __attribute__((ext_vector_type(8)));
typedef float f32x4 __attribute__((ext_vector_type(4)));

__device__ __forceinline__ unsigned short f2bf(float f) {
    union { float f; unsigned u; } v; v.f = f;
    unsigned u = v.u;
    u += 0x7FFFu + ((u >> 16) & 1u);   // RNE
    return (unsigned short)(u >> 16);
}
__device__ __forceinline__ bf16x8 pack8(float4 a, float4 b) {
    union { bf16x8 v; __hip_bfloat162 h[4]; } u;
    u.h[0] = __float22bfloat162_rn(make_float2(a.x, a.y));
    u.h[1] = __float22bfloat162_rn(make_float2(a.z, a.w));
    u.h[2] = __float22bfloat162_rn(make_float2(b.x, b.y));
    u.h[3] = __float22bfloat162_rn(make_float2(b.z, b.w));
    return u.v;
}

// ---------------------------------------------------------------------------
// Kernel 1: G columns, one block per column (unchanged from R3).
// ---------------------------------------------------------------------------
#define AST 258
__global__ __launch_bounds__(256) void make_G3(const float* __restrict__ A,
                                               unsigned short* __restrict__ Gt) {
    __shared__ unsigned short As[256 * AST];   // 129 KB
    const int tid = threadIdx.x;
    const int l = tid & 63;
    const int wv = tid >> 6;

    for (int it = 0; it < 64; ++it) {
        const int r = it * 4 + wv;
        const int c0 = l * 4;
        float4 v = *(const float4*)(A + r * 256 + c0);
        *(ushort2*)(&As[r * AST + c0])     = make_ushort2(f2bf(v.x), f2bf(v.y));
        *(ushort2*)(&As[r * AST + c0 + 2]) = make_ushort2(f2bf(v.z), f2bf(v.w));
    }
    __syncthreads();
    if (wv != 0) return;

    const int c = blockIdx.x;
    float p[4];
#pragma unroll
    for (int k = 0; k < 4; ++k) p[k] = (64 * k + l == c) ? 1.f : 0.f;

#pragma unroll
    for (int kb = 0; kb < 4; ++kb) {
#pragma unroll 8
        for (int i2 = 0; i2 < 32; ++i2) {
            unsigned u[4];
#pragma unroll
            for (int k = 0; k < 4; ++k)
                if (k >= kb)
                    u[k] = *(const unsigned*)(&As[(64 * k + l) * AST + kb * 64 + 2 * i2]);
            const int t0 = 2 * i2, t1 = t0 + 1;
            float s0 = __int_as_float(__builtin_amdgcn_readlane(__float_as_int(p[kb]), t0));
            p[kb] += (l > t0 ? __int_as_float(u[kb] << 16) : 0.f) * s0;
#pragma unroll
            for (int k = 0; k < 4; ++k)
                if (k > kb) p[k] += __int_as_float(u[k] << 16) * s0;
            float s1 = __int_as_float(__builtin_amdgcn_readlane(__float_as_int(p[kb]), t1));
            p[kb] += (l > t1 ? __int_as_float(u[kb] & 0xffff0000u) : 0.f) * s1;
#pragma unroll
            for (int k = 0; k < 4; ++k)
                if (k > kb) p[k] += __int_as_float(u[k] & 0xffff0000u) * s1;
        }
    }
#pragma unroll
    for (int k = 0; k < 4; ++k)
        Gt[c * 256 + 64 * k + l] = f2bf(p[k]);
}

// ---------------------------------------------------------------------------
// Kernel 2: Out = Z @ G. 512 blocks (256 M-tiles x 2 N-halves) x 512 thr.
// Gs: 128 local cols x 256 K bf16, dense (64 KB), 16B-granule XOR swizzle
//   gs = g ^ (localcol & 7)  -> B-frag reads 2-way max (free).
// Wave = 16 rows x 128 cols, K=256 in two pipelined halves. No barriers
// after the single G-staging sync; 4 M-iterations per block.
// ---------------------------------------------------------------------------
__global__ __launch_bounds__(512, 4) void scm_gemm4(const float* __restrict__ Z,
                                                    const unsigned short* __restrict__ Gt,
                                                    float* __restrict__ Out) {
    __shared__ __align__(16) unsigned short Gs[128 * 256];   // 64 KB
    const int tid = threadIdx.x;
    const int lane = tid & 63;
    const int wave = tid >> 6;
    const int n = lane & 15;
    const int quad = lane >> 4;
    const int bn = (blockIdx.x & 1) * 128;                 // N-half
    const size_t blockRow = (size_t)(blockIdx.x >> 1) * 512;

    // ---- stage G half (64 KB): 4096 granules / 512 thr = 8 each ----
#pragma unroll
    for (int it = 0; it < 8; ++it) {
        const int chunk = it * 512 + tid;
        const int row = chunk >> 5;            // local col 0..127
        const int g = chunk & 31;
        const int gs = g ^ (row & 7);
        uint4 v = *(const uint4*)(Gt + (bn + row) * 256 + g * 8);
        *(uint4*)(&Gs[row * 256 + gs * 8]) = v;
    }
    __syncthreads();

    const int swz = n & 7;
    const float* zbase = Z + (blockRow + wave * 16 + n) * 256 + quad * 8;
    float* obase = Out + (blockRow + wave * 16 + quad * 4) * 256 + bn + n;

    f32x4 acc[8];
#pragma unroll
    for (int nt = 0; nt < 8; ++nt) {
        f32x4 zero = {0.f, 0.f, 0.f, 0.f};
        acc[nt] = zero;
    }

    float4 zf[8];
    // preload iter0 K-lo
#pragma unroll
    for (int kk = 0; kk < 4; ++kk) {
        zf[2 * kk]     = *(const float4*)(zbase + kk * 32);
        zf[2 * kk + 1] = *(const float4*)(zbase + kk * 32 + 4);
    }

    for (int i = 0; i < 4; ++i) {
        const float* zi = zbase + (size_t)i * 128 * 256;
        // pack K-lo (waits on its loads), free zf
        bf16x8 af[4];
#pragma unroll
        for (int kk = 0; kk < 4; ++kk) af[kk] = pack8(zf[2 * kk], zf[2 * kk + 1]);
        // issue K-hi loads for iter i
#pragma unroll
        for (int kk = 0; kk < 4; ++kk) {
            zf[2 * kk]     = *(const float4*)(zi + 128 + kk * 32);
            zf[2 * kk + 1] = *(const float4*)(zi + 128 + kk * 32 + 4);
        }
        // MFMA K-lo: kk maps to k-offset kk*32 (+ quad*8)
#pragma unroll
        for (int kk = 0; kk < 4; ++kk)
#pragma unroll
            for (int nt = 0; nt < 8; ++nt) {
                const bf16x8 b = *(const bf16x8*)(
                    &Gs[(nt * 16 + n) * 256 + ((kk * 4 + quad) ^ swz) * 8]);
                acc[nt] = __builtin_amdgcn_mfma_f32_16x16x32_bf16(af[kk], b, acc[nt], 0, 0, 0);
            }
        // pack K-hi
#pragma unroll
        for (int kk = 0; kk < 4; ++kk) af[kk] = pack8(zf[2 * kk], zf[2 * kk + 1]);
        // issue next iter K-lo loads
        if (i < 3) {
            const float* zn = zbase + (size_t)(i + 1) * 128 * 256;
#pragma unroll
            for (int kk = 0; kk < 4; ++kk) {
                zf[2 * kk]     = *(const float4*)(zn + kk * 32);
                zf[2 * kk + 1] = *(const float4*)(zn + kk * 32 + 4);
            }
        }
        // MFMA K-hi: k-offset 128 + kk*32 -> granules 16 + kk*4 + quad
#pragma unroll
        for (int kk = 0; kk < 4; ++kk)
#pragma unroll
            for (int nt = 0; nt < 8; ++nt) {
                const bf16x8 b = *(const bf16x8*)(
                    &Gs[(nt * 16 + n) * 256 + (((16 + kk * 4 + quad)) ^ swz) * 8]);
                acc[nt] = __builtin_amdgcn_mfma_f32_16x16x32_bf16(af[kk], b, acc[nt], 0, 0, 0);
            }
        // store + re-zero. C/D layout: col = lane&15, row = quad*4 + r.
        float* oi = obase + (size_t)i * 128 * 256;
#pragma unroll
        for (int nt = 0; nt < 8; ++nt)
#pragma unroll
            for (int r = 0; r < 4; ++r) {
                oi[(size_t)r * 256 + nt * 16] = acc[nt][r];
                acc[nt][r] = 0.f;
            }
    }
}

extern "C" void kernel_launch(void* const* d_in, const int* in_sizes, int n_in,
                              void* d_out, int out_size, void* d_ws, size_t ws_size,
                              hipStream_t stream) {
    const float* Z = (const float*)d_in[0];       // [131072 x 256]
    const float* A = (const float*)d_in[1];       // [256 x 256]
    float* Out = (float*)d_out;                   // [131072 x 256]
    unsigned short* Gt = (unsigned short*)d_ws;   // 256*256 bf16 = 128 KB

    hipLaunchKernelGGL(make_G3, dim3(256), dim3(256), 0, stream, A, Gt);
    hipLaunchKernelGGL(scm_gemm4, dim3(512), dim3(512), 0, stream, Z, Gt, Out);
}